// Round 5
// baseline (410.622 us; speedup 1.0000x reference)
//
#include <hip/hip_runtime.h>
#include <hip/hip_bf16.h>
#include <math.h>

typedef __bf16 bf16;
typedef __bf16 bf16x8 __attribute__((ext_vector_type(8)));
typedef float f32x4 __attribute__((ext_vector_type(4)));

#define SEQ 2048
#define NHEADS 16
#define HDIM 64
#define DM 1024
#define NEGBIG -1.0e30f

__device__ __forceinline__ void gload_lds16(const void* g, void* l) {
  __builtin_amdgcn_global_load_lds(
      (const __attribute__((address_space(1))) unsigned int*)g,
      (__attribute__((address_space(3))) unsigned int*)l, 16, 0, 0);
}

// -------- elementwise f32 -> bf16 (hidden_states), 8 elems/thread ----------
__global__ __launch_bounds__(256) void cvt_f32_bf16(
    const float* __restrict__ in, bf16* __restrict__ out) {
  int i = (blockIdx.x * 256 + threadIdx.x) * 8;
  float4 a = *(const float4*)(in + i);
  float4 b = *(const float4*)(in + i + 4);
  bf16x8 o;
  o[0] = (bf16)a.x; o[1] = (bf16)a.y; o[2] = (bf16)a.z; o[3] = (bf16)a.w;
  o[4] = (bf16)b.x; o[5] = (bf16)b.y; o[6] = (bf16)b.z; o[7] = (bf16)b.w;
  *(bf16x8*)(out + i) = o;
}

// -------- transpose [R,C] f32 -> [C,R] bf16 ---------------------------------
__global__ __launch_bounds__(256) void transpose_f32_bf16(
    const float* __restrict__ in, bf16* __restrict__ out, int R, int C) {
  __shared__ float tile[64][65];
  int t = threadIdx.x;
  int c0 = blockIdx.x * 64, r0 = blockIdx.y * 64;
  int col = t & 63, rb = (t >> 6) * 16;
#pragma unroll
  for (int i = 0; i < 16; ++i)
    tile[rb + i][col] = in[(size_t)(r0 + rb + i) * C + c0 + col];
  __syncthreads();
#pragma unroll
  for (int i = 0; i < 16; ++i)
    out[(size_t)(c0 + rb + i) * R + r0 + col] = (bf16)tile[col][rb + i];
}

// ---------------- GEMM C = A[M,K] * B[K,N], B given transposed Bt[N,K] ------
// 128x128 tile, BK=32, 4 waves (2x2), each wave 64x64 via 4x4 MFMA 16x16x32.
// EPI==0: f32 store to C (final output).
// EPI==1: QKV epilogue, 3D RoPE on Q/K -> q_ws,k_ws [B,H,S,D]; V -> vT_ws [B,H,D,S].
template <int EPI>
__global__ __launch_bounds__(256) void gemm_bt(
    const bf16* __restrict__ A, const bf16* __restrict__ Bt,
    float* __restrict__ C, int M, int N, int K,
    bf16* __restrict__ q_ws, bf16* __restrict__ k_ws, bf16* __restrict__ vT_ws,
    const int* __restrict__ pos) {
  __shared__ __align__(16) bf16 a_lds[128 * 32];
  __shared__ __align__(16) bf16 b_lds[128 * 32];
  int tid = threadIdx.x;
  int wave = tid >> 6, lane = tid & 63;
  int quad = lane >> 4, l15 = lane & 15;
  int wm = wave >> 1, wn = wave & 1;
  int m0 = blockIdx.y * 128, n0 = blockIdx.x * 128;

  f32x4 acc[4][4] = {};

  for (int kt = 0; kt < K; kt += 32) {
    __syncthreads();  // protect LDS from previous iteration's readers
#pragma unroll
    for (int call = 0; call < 2; ++call) {
      int chunk = call * 256 + tid;
      int row = chunk >> 2, cc = (chunk & 3) * 8;
      gload_lds16(A + (size_t)(m0 + row) * K + kt + cc,
                  (char*)a_lds + call * 4096 + wave * 1024);
      gload_lds16(Bt + (size_t)(n0 + row) * K + kt + cc,
                  (char*)b_lds + call * 4096 + wave * 1024);
    }
    __syncthreads();  // staging complete (compiler drains vmcnt before barrier)
    bf16x8 af[4], bfr[4];
#pragma unroll
    for (int i = 0; i < 4; ++i) {
      af[i]  = *(const bf16x8*)(a_lds + (wm * 64 + i * 16 + l15) * 32 + quad * 8);
      bfr[i] = *(const bf16x8*)(b_lds + (wn * 64 + i * 16 + l15) * 32 + quad * 8);
    }
#pragma unroll
    for (int mi = 0; mi < 4; ++mi)
#pragma unroll
      for (int ni = 0; ni < 4; ++ni)
        acc[mi][ni] = __builtin_amdgcn_mfma_f32_16x16x32_bf16(
            af[mi], bfr[ni], acc[mi][ni], 0, 0, 0);
  }

  // C/D layout: col = lane&15, row = quad*4 + reg  (m89-verified)
  if (EPI == 0) {
#pragma unroll
    for (int mi = 0; mi < 4; ++mi) {
      int mb = m0 + wm * 64 + mi * 16 + quad * 4;
#pragma unroll
      for (int ni = 0; ni < 4; ++ni) {
        int n = n0 + wn * 64 + ni * 16 + l15;
#pragma unroll
        for (int r = 0; r < 4; ++r)
          C[(size_t)(mb + r) * N + n] = acc[mi][ni][r];
      }
    }
  } else {
    const float LN1E4 = 9.210340371976184f;  // ln(10000)
#pragma unroll
    for (int mi = 0; mi < 4; ++mi) {
#pragma unroll
      for (int r = 0; r < 4; ++r) {
        int m = m0 + wm * 64 + mi * 16 + quad * 4 + r;
        int b = m >> 11, s = m & 2047;
        int px = pos[m * 3 + 0], py = pos[m * 3 + 1], pz = pos[m * 3 + 2];
        px = px < 0 ? 0 : (px > 31 ? 31 : px);
        py = py < 0 ? 0 : (py > 31 ? 31 : py);
        pz = pz < 0 ? 0 : (pz > 7 ? 7 : pz);
#pragma unroll
        for (int ni = 0; ni < 4; ++ni) {
          int n = n0 + wn * 64 + ni * 16 + l15;
          float v = acc[mi][ni][r];
          float partner = __shfl_xor(v, 1, 64);  // col n^1, same row/reg
          int which = n >> 10, nn = n & 1023, h = nn >> 6, hd = nn & 63;
          if (which == 2) {  // V: store transposed [B,H,D,S] for attention PV
            vT_ws[((size_t)(b * NHEADS + h) * HDIM + hd) * SEQ + s] = (bf16)v;
          } else {           // Q/K: 3D RoPE, store [B,H,S,D]
            int i = hd >> 1, p, d, iloc;
            if (hd < 20)      { p = px; d = 20; iloc = i; }
            else if (hd < 40) { p = py; d = 20; iloc = i - 10; }
            else              { p = pz; d = 24; iloc = i - 20; }
            float invf = __expf(-((float)(2 * iloc) / (float)d) * LN1E4);
            float ang = (float)p * invf;
            float sn, cs;
            __sincosf(ang, &sn, &cs);
            float outv =
                (hd & 1) ? (v * cs + partner * sn) : (v * cs - partner * sn);
            bf16* dst = (which == 0) ? q_ws : k_ws;
            dst[((size_t)(b * NHEADS + h) * SEQ + s) * HDIM + hd] = (bf16)outv;
          }
        }
      }
    }
  }
}

// ---------------- causal flash attention, D=64, 64 Q-rows per block ---------
// 4 waves; wave w owns Q rows [q0+w*16, q0+w*16+16) fully independently:
// no __syncthreads in the KV loop. K read direct from global [B,H,S,D];
// V read direct from global V^T [B,H,D,S]. P round-trips via per-wave LDS
// strip, ordered by __threadfence_block (fence + lgkmcnt drain; no barrier).
__global__ __launch_bounds__(256) void attn_fwd(
    const bf16* __restrict__ Q, const bf16* __restrict__ K,
    const bf16* __restrict__ VT, bf16* __restrict__ O) {
  __shared__ __align__(16) bf16 p_lds[64 * 72];  // [64 q rows][64 kv], stride 72
  int tid = threadIdx.x;
  int wave = tid >> 6, lane = tid & 63;
  int quad = lane >> 4, l15 = lane & 15;
  int qt = (int)gridDim.x - 1 - (int)blockIdx.x;  // heavy blocks dispatch first
  int bh = blockIdx.y;
  int q0 = qt * 64;
  size_t base = (size_t)bh * SEQ * HDIM;
  const bf16* Qb = Q + base;
  const bf16* Kb = K + base;
  const bf16* VTb = VT + base;  // [HDIM][SEQ]
  bf16* pw = p_lds + wave * 16 * 72;  // this wave's private strip

  // Q A-frags: m = l15 (wave-local row), k = d
  bf16x8 qf0 = *(const bf16x8*)(Qb + (size_t)(q0 + wave * 16 + l15) * HDIM + quad * 8);
  bf16x8 qf1 = *(const bf16x8*)(Qb + (size_t)(q0 + wave * 16 + l15) * HDIM + 32 + quad * 8);

  f32x4 o_acc[4] = {};
  float m_i[4], l_i[4];
#pragma unroll
  for (int r = 0; r < 4; ++r) { m_i[r] = NEGBIG; l_i[r] = 0.f; }
  int qrow[4];
#pragma unroll
  for (int r = 0; r < 4; ++r) qrow[r] = q0 + wave * 16 + quad * 4 + r;

  for (int tkv = 0; tkv <= qt; ++tkv) {
    int kv0 = tkv * 64;
    // S = Q K^T for this wave's 16 rows (K B-frags direct from global, L2-hot)
    f32x4 s_acc[4];
#pragma unroll
    for (int nt = 0; nt < 4; ++nt) {
      int krow = kv0 + nt * 16 + l15;
      bf16x8 kf0 = *(const bf16x8*)(Kb + (size_t)krow * HDIM + quad * 8);
      bf16x8 kf1 = *(const bf16x8*)(Kb + (size_t)krow * HDIM + 32 + quad * 8);
      f32x4 z = {};
      z = __builtin_amdgcn_mfma_f32_16x16x32_bf16(qf0, kf0, z, 0, 0, 0);
      z = __builtin_amdgcn_mfma_f32_16x16x32_bf16(qf1, kf1, z, 0, 0, 0);
      s_acc[nt] = z;
    }
    bool diag = (tkv == qt);
#pragma unroll
    for (int r = 0; r < 4; ++r) {
      float mx = NEGBIG;
#pragma unroll
      for (int nt = 0; nt < 4; ++nt) {
        float v = fminf(s_acc[nt][r] * 0.125f, 3.0e38f);  // clamp: no +inf ever
        if (diag && (kv0 + nt * 16 + l15 > qrow[r])) v = NEGBIG;
        s_acc[nt][r] = v;
        mx = fmaxf(mx, v);
      }
#pragma unroll
      for (int off = 1; off < 16; off <<= 1)
        mx = fmaxf(mx, __shfl_xor(mx, off, 64));
      float mnew = fmaxf(m_i[r], mx);
      float alpha = __expf(m_i[r] - mnew);  // finite - finite: no NaN possible
      float rs = 0.f;
#pragma unroll
      for (int nt = 0; nt < 4; ++nt) {
        float p = __expf(s_acc[nt][r] - mnew);
        s_acc[nt][r] = p;
        rs += p;
      }
#pragma unroll
      for (int off = 1; off < 16; off <<= 1) rs += __shfl_xor(rs, off, 64);
      l_i[r] = l_i[r] * alpha + rs;
      m_i[r] = mnew;
#pragma unroll
      for (int nt = 0; nt < 4; ++nt) o_acc[nt][r] *= alpha;
#pragma unroll
      for (int nt = 0; nt < 4; ++nt)
        pw[(quad * 4 + r) * 72 + nt * 16 + l15] = (bf16)s_acc[nt][r];
    }
    // Order wave-private scalar stores before vector re-reads: compiler fence
    // + s_waitcnt lgkmcnt(0). No inter-wave barrier needed (strip is private).
    __threadfence_block();
    // PV: A-frags from own strip, B-frags direct from global V^T (k-contiguous)
    bf16x8 pf0 = *(const bf16x8*)(pw + l15 * 72 + quad * 8);
    bf16x8 pf1 = *(const bf16x8*)(pw + l15 * 72 + 32 + quad * 8);
#pragma unroll
    for (int nt = 0; nt < 4; ++nt) {
      const bf16* vrow = VTb + (size_t)(nt * 16 + l15) * SEQ + kv0;
      bf16x8 vf0 = *(const bf16x8*)(vrow + quad * 8);
      bf16x8 vf1 = *(const bf16x8*)(vrow + 32 + quad * 8);
      o_acc[nt] = __builtin_amdgcn_mfma_f32_16x16x32_bf16(pf0, vf0, o_acc[nt], 0, 0, 0);
      o_acc[nt] = __builtin_amdgcn_mfma_f32_16x16x32_bf16(pf1, vf1, o_acc[nt], 0, 0, 0);
    }
  }
  // epilogue: normalize, store into [B, S, H*D] layout for the out-proj GEMM
  int b = bh >> 4, h = bh & 15;
#pragma unroll
  for (int r = 0; r < 4; ++r) {
    float inv = 1.f / l_i[r];
    int s = q0 + wave * 16 + quad * 4 + r;
#pragma unroll
    for (int nt = 0; nt < 4; ++nt) {
      int d = nt * 16 + l15;
      O[((size_t)(b * SEQ + s)) * DM + h * HDIM + d] = (bf16)(o_acc[nt][r] * inv);
    }
  }
}

extern "C" void kernel_launch(void* const* d_in, const int* in_sizes, int n_in,
                              void* d_out, int out_size, void* d_ws,
                              size_t ws_size, hipStream_t stream) {
  const float* hidden = (const float*)d_in[0];   // [2,2048,1024] f32
  const float* w_qkv  = (const float*)d_in[1];   // [1024,3072]  f32
  const float* w_out  = (const float*)d_in[2];   // [1024,1024]  f32
  const int*   pos    = (const int*)d_in[3];     // [2,2048,3]   i32
  float* out = (float*)d_out;                    // f32 output

  char* ws = (char*)d_ws;
  bf16* wqkvT  = (bf16*)ws;  ws += (size_t)3072 * 1024 * 2;
  bf16* woutT  = (bf16*)ws;  ws += (size_t)1024 * 1024 * 2;
  bf16* hid_bf = (bf16*)ws;  ws += (size_t)4096 * 1024 * 2;
  bf16* q_ws   = (bf16*)ws;  ws += (size_t)32 * SEQ * HDIM * 2;
  bf16* k_ws   = (bf16*)ws;  ws += (size_t)32 * SEQ * HDIM * 2;
  bf16* vT_ws  = (bf16*)ws;  ws += (size_t)32 * SEQ * HDIM * 2;
  bf16* attn_ws = (bf16*)ws;  // [4096, 1024]

  cvt_f32_bf16<<<dim3(2048), 256, 0, stream>>>(hidden, hid_bf);
  transpose_f32_bf16<<<dim3(48, 16), 256, 0, stream>>>(w_qkv, wqkvT, 1024, 3072);
  transpose_f32_bf16<<<dim3(16, 16), 256, 0, stream>>>(w_out, woutT, 1024, 1024);
  gemm_bt<1><<<dim3(24, 32), 256, 0, stream>>>(
      hid_bf, wqkvT, nullptr, 4096, 3072, 1024, q_ws, k_ws, vT_ws, pos);
  attn_fwd<<<dim3(32, 32), 256, 0, stream>>>(q_ws, k_ws, vT_ws, attn_ws);
  gemm_bt<0><<<dim3(8, 32), 256, 0, stream>>>(
      attn_ws, woutT, out, 4096, 1024, 1024, nullptr, nullptr, nullptr, nullptr);
}

// Round 6
// 227.827 us; speedup vs baseline: 1.8023x; 1.8023x over previous
//
#include <hip/hip_runtime.h>
#include <hip/hip_bf16.h>
#include <math.h>

typedef __bf16 bf16;
typedef __bf16 bf16x8 __attribute__((ext_vector_type(8)));
typedef float f32x4 __attribute__((ext_vector_type(4)));

#define SEQ 2048
#define NHEADS 16
#define HDIM 64
#define DM 1024
#define NEGBIG -1.0e30f

__device__ __forceinline__ void gload_lds16(const void* g, void* l) {
  __builtin_amdgcn_global_load_lds(
      (const __attribute__((address_space(1))) unsigned int*)g,
      (__attribute__((address_space(3))) unsigned int*)l, 16, 0, 0);
}

// DPP lane-row (16-lane) reductions: quad_perm xor1 (0xB1), xor2 (0x4E),
// row_ror:4 (0x124), row_ror:8 (0x128). Pure VALU — no LDS round trips.
template <int CTRL>
__device__ __forceinline__ float dppmovf(float x) {
  return __builtin_bit_cast(
      float, __builtin_amdgcn_mov_dpp(__builtin_bit_cast(int, x), CTRL, 0xf,
                                      0xf, true));
}
__device__ __forceinline__ float rowmax16(float x) {
  x = fmaxf(x, dppmovf<0xB1>(x));
  x = fmaxf(x, dppmovf<0x4E>(x));
  x = fmaxf(x, dppmovf<0x124>(x));
  x = fmaxf(x, dppmovf<0x128>(x));
  return x;
}
__device__ __forceinline__ float rowsum16(float x) {
  x += dppmovf<0xB1>(x);
  x += dppmovf<0x4E>(x);
  x += dppmovf<0x124>(x);
  x += dppmovf<0x128>(x);
  return x;
}

// -------- elementwise f32 -> bf16 (hidden_states), 8 elems/thread ----------
__global__ __launch_bounds__(256) void cvt_f32_bf16(
    const float* __restrict__ in, bf16* __restrict__ out) {
  int i = (blockIdx.x * 256 + threadIdx.x) * 8;
  float4 a = *(const float4*)(in + i);
  float4 b = *(const float4*)(in + i + 4);
  bf16x8 o;
  o[0] = (bf16)a.x; o[1] = (bf16)a.y; o[2] = (bf16)a.z; o[3] = (bf16)a.w;
  o[4] = (bf16)b.x; o[5] = (bf16)b.y; o[6] = (bf16)b.z; o[7] = (bf16)b.w;
  *(bf16x8*)(out + i) = o;
}

// -------- transpose [R,C] f32 -> [C,R] bf16 ---------------------------------
__global__ __launch_bounds__(256) void transpose_f32_bf16(
    const float* __restrict__ in, bf16* __restrict__ out, int R, int C) {
  __shared__ float tile[64][65];
  int t = threadIdx.x;
  int c0 = blockIdx.x * 64, r0 = blockIdx.y * 64;
  int col = t & 63, rb = (t >> 6) * 16;
#pragma unroll
  for (int i = 0; i < 16; ++i)
    tile[rb + i][col] = in[(size_t)(r0 + rb + i) * C + c0 + col];
  __syncthreads();
#pragma unroll
  for (int i = 0; i < 16; ++i)
    out[(size_t)(c0 + rb + i) * R + r0 + col] = (bf16)tile[col][rb + i];
}

// ---------------- GEMM C = A[M,K] * B[K,N], B given transposed Bt[N,K] ------
// 128x128 tile, BK=32, 4 waves (2x2), each wave 64x64 via 4x4 MFMA 16x16x32.
// EPI==0: f32 store to C (final output).
// EPI==1: QKV epilogue, 3D RoPE on Q/K -> q_ws,k_ws [B,H,S,D]; V -> vT_ws [B,H,D,S].
template <int EPI>
__global__ __launch_bounds__(256) void gemm_bt(
    const bf16* __restrict__ A, const bf16* __restrict__ Bt,
    float* __restrict__ C, int M, int N, int K,
    bf16* __restrict__ q_ws, bf16* __restrict__ k_ws, bf16* __restrict__ vT_ws,
    const int* __restrict__ pos) {
  __shared__ __align__(16) bf16 a_lds[128 * 32];
  __shared__ __align__(16) bf16 b_lds[128 * 32];
  int tid = threadIdx.x;
  int wave = tid >> 6, lane = tid & 63;
  int quad = lane >> 4, l15 = lane & 15;
  int wm = wave >> 1, wn = wave & 1;
  int m0 = blockIdx.y * 128, n0 = blockIdx.x * 128;

  f32x4 acc[4][4] = {};

  for (int kt = 0; kt < K; kt += 32) {
    __syncthreads();
#pragma unroll
    for (int call = 0; call < 2; ++call) {
      int chunk = call * 256 + tid;
      int row = chunk >> 2, cc = (chunk & 3) * 8;
      gload_lds16(A + (size_t)(m0 + row) * K + kt + cc,
                  (char*)a_lds + call * 4096 + wave * 1024);
      gload_lds16(Bt + (size_t)(n0 + row) * K + kt + cc,
                  (char*)b_lds + call * 4096 + wave * 1024);
    }
    __syncthreads();
    bf16x8 af[4], bfr[4];
#pragma unroll
    for (int i = 0; i < 4; ++i) {
      af[i]  = *(const bf16x8*)(a_lds + (wm * 64 + i * 16 + l15) * 32 + quad * 8);
      bfr[i] = *(const bf16x8*)(b_lds + (wn * 64 + i * 16 + l15) * 32 + quad * 8);
    }
#pragma unroll
    for (int mi = 0; mi < 4; ++mi)
#pragma unroll
      for (int ni = 0; ni < 4; ++ni)
        acc[mi][ni] = __builtin_amdgcn_mfma_f32_16x16x32_bf16(
            af[mi], bfr[ni], acc[mi][ni], 0, 0, 0);
  }

  // C/D layout: col = lane&15, row = quad*4 + reg  (m89-verified)
  if (EPI == 0) {
#pragma unroll
    for (int mi = 0; mi < 4; ++mi) {
      int mb = m0 + wm * 64 + mi * 16 + quad * 4;
#pragma unroll
      for (int ni = 0; ni < 4; ++ni) {
        int n = n0 + wn * 64 + ni * 16 + l15;
#pragma unroll
        for (int r = 0; r < 4; ++r)
          C[(size_t)(mb + r) * N + n] = acc[mi][ni][r];
      }
    }
  } else {
    const float LN1E4 = 9.210340371976184f;  // ln(10000)
#pragma unroll
    for (int mi = 0; mi < 4; ++mi) {
#pragma unroll
      for (int r = 0; r < 4; ++r) {
        int m = m0 + wm * 64 + mi * 16 + quad * 4 + r;
        int b = m >> 11, s = m & 2047;
        int px = pos[m * 3 + 0], py = pos[m * 3 + 1], pz = pos[m * 3 + 2];
        px = px < 0 ? 0 : (px > 31 ? 31 : px);
        py = py < 0 ? 0 : (py > 31 ? 31 : py);
        pz = pz < 0 ? 0 : (pz > 7 ? 7 : pz);
#pragma unroll
        for (int ni = 0; ni < 4; ++ni) {
          int n = n0 + wn * 64 + ni * 16 + l15;
          float v = acc[mi][ni][r];
          float partner = __shfl_xor(v, 1, 64);  // col n^1, same row/reg
          int which = n >> 10, nn = n & 1023, h = nn >> 6, hd = nn & 63;
          if (which == 2) {  // V: store transposed [B,H,D,S] for attention PV
            vT_ws[((size_t)(b * NHEADS + h) * HDIM + hd) * SEQ + s] = (bf16)v;
          } else {           // Q/K: 3D RoPE, store [B,H,S,D]
            int i = hd >> 1, p, d, iloc;
            if (hd < 20)      { p = px; d = 20; iloc = i; }
            else if (hd < 40) { p = py; d = 20; iloc = i - 10; }
            else              { p = pz; d = 24; iloc = i - 20; }
            float invf = __expf(-((float)(2 * iloc) / (float)d) * LN1E4);
            float ang = (float)p * invf;
            float sn, cs;
            __sincosf(ang, &sn, &cs);
            float outv =
                (hd & 1) ? (v * cs + partner * sn) : (v * cs - partner * sn);
            bf16* dst = (which == 0) ? q_ws : k_ws;
            dst[((size_t)(b * NHEADS + h) * SEQ + s) * HDIM + hd] = (bf16)outv;
          }
        }
      }
    }
  }
}

// ---------------- causal flash attention, D=64, 64 Q-rows per block ---------
// 1D grid of 1024: bh = idx&31 (XCD-pinned: idx%8 == bh%8 -> one bh's K/V
// stays in one XCD L2), qt = 31-(idx>>5) (heavy blocks first).
// K,V cooperatively staged in LDS (coalesced b128 both sides); softmax
// reductions via DPP (no LDS); P round-trip via wave-private LDS strip.
__global__ __launch_bounds__(256) void attn_fwd(
    const bf16* __restrict__ Q, const bf16* __restrict__ K,
    const bf16* __restrict__ VT, bf16* __restrict__ O) {
  __shared__ __align__(16) bf16 k_lds[64 * 72];  // [kv row][d], stride 72
  __shared__ __align__(16) bf16 v_lds[64 * 72];  // [d][kv], stride 72
  __shared__ __align__(16) bf16 p_lds[64 * 72];  // [q row][kv], stride 72
  int tid = threadIdx.x;
  int wave = tid >> 6, lane = tid & 63;
  int quad = lane >> 4, l15 = lane & 15;
  int idx = blockIdx.x;
  int bh = idx & 31;          // XCD pinning
  int qt = 31 - (idx >> 5);   // heavy first
  int q0 = qt * 64;
  size_t base = (size_t)bh * SEQ * HDIM;
  const bf16* Qb = Q + base;
  const bf16* Kb = K + base;
  const bf16* VTb = VT + base;  // [HDIM][SEQ]
  bf16* pw = p_lds + wave * 16 * 72;  // this wave's private strip

  // Q A-frags: m = l15 (wave-local row), k = d
  bf16x8 qf0 = *(const bf16x8*)(Qb + (size_t)(q0 + wave * 16 + l15) * HDIM + quad * 8);
  bf16x8 qf1 = *(const bf16x8*)(Qb + (size_t)(q0 + wave * 16 + l15) * HDIM + 32 + quad * 8);

  // staging addresses: thread handles 16B chunks c0, c0+1 (same row)
  int c0 = tid * 2;
  int srow = c0 >> 3;          // 0..63
  int soff = (c0 & 7) * 8;     // 0,16,32,48 (c0 even)

  f32x4 o_acc[4] = {};
  float m_i[4], l_i[4];
#pragma unroll
  for (int r = 0; r < 4; ++r) { m_i[r] = NEGBIG; l_i[r] = 0.f; }
  int qrow[4];
#pragma unroll
  for (int r = 0; r < 4; ++r) qrow[r] = q0 + wave * 16 + quad * 4 + r;

  for (int tkv = 0; tkv <= qt; ++tkv) {
    int kv0 = tkv * 64;
    __syncthreads();  // prev iteration's k/v readers done
    {  // stage K tile [kv][d] and V^T tile [d][kv], coalesced both sides
      const bf16* ksrc = Kb + (size_t)(kv0 + srow) * HDIM + soff;
      const bf16* vsrc = VTb + (size_t)srow * SEQ + kv0 + soff;
      bf16x8 ka = *(const bf16x8*)ksrc, kb2 = *(const bf16x8*)(ksrc + 8);
      bf16x8 va = *(const bf16x8*)vsrc, vb2 = *(const bf16x8*)(vsrc + 8);
      *(bf16x8*)(k_lds + srow * 72 + soff) = ka;
      *(bf16x8*)(k_lds + srow * 72 + soff + 8) = kb2;
      *(bf16x8*)(v_lds + srow * 72 + soff) = va;
      *(bf16x8*)(v_lds + srow * 72 + soff + 8) = vb2;
    }
    __syncthreads();  // staging complete
    // S = Q K^T for this wave's 16 rows
    f32x4 s_acc[4];
#pragma unroll
    for (int nt = 0; nt < 4; ++nt) {
      const bf16* krow_p = k_lds + (nt * 16 + l15) * 72;
      bf16x8 kf0 = *(const bf16x8*)(krow_p + quad * 8);
      bf16x8 kf1 = *(const bf16x8*)(krow_p + 32 + quad * 8);
      f32x4 z = {};
      z = __builtin_amdgcn_mfma_f32_16x16x32_bf16(qf0, kf0, z, 0, 0, 0);
      z = __builtin_amdgcn_mfma_f32_16x16x32_bf16(qf1, kf1, z, 0, 0, 0);
      s_acc[nt] = z;
    }
    bool diag = (tkv == qt);
#pragma unroll
    for (int r = 0; r < 4; ++r) {
      float mx = NEGBIG;
#pragma unroll
      for (int nt = 0; nt < 4; ++nt) {
        float v = fminf(s_acc[nt][r] * 0.125f, 3.0e38f);
        if (diag && (kv0 + nt * 16 + l15 > qrow[r])) v = NEGBIG;
        s_acc[nt][r] = v;
        mx = fmaxf(mx, v);
      }
      mx = rowmax16(mx);  // DPP, no LDS
      float mnew = fmaxf(m_i[r], mx);
      float alpha = __expf(m_i[r] - mnew);
      float rs = 0.f;
#pragma unroll
      for (int nt = 0; nt < 4; ++nt) {
        float p = __expf(s_acc[nt][r] - mnew);
        s_acc[nt][r] = p;
        rs += p;
      }
      rs = rowsum16(rs);  // DPP, no LDS
      l_i[r] = l_i[r] * alpha + rs;
      m_i[r] = mnew;
#pragma unroll
      for (int nt = 0; nt < 4; ++nt) o_acc[nt][r] *= alpha;
#pragma unroll
      for (int nt = 0; nt < 4; ++nt)
        pw[(quad * 4 + r) * 72 + nt * 16 + l15] = (bf16)s_acc[nt][r];
    }
    // wave-private p strip: order scalar writes before vector reads
    __asm__ volatile("s_waitcnt lgkmcnt(0)" ::: "memory");
    bf16x8 pf0 = *(const bf16x8*)(pw + l15 * 72 + quad * 8);
    bf16x8 pf1 = *(const bf16x8*)(pw + l15 * 72 + 32 + quad * 8);
#pragma unroll
    for (int nt = 0; nt < 4; ++nt) {
      const bf16* vrow = v_lds + (nt * 16 + l15) * 72;
      bf16x8 vf0 = *(const bf16x8*)(vrow + quad * 8);
      bf16x8 vf1 = *(const bf16x8*)(vrow + 32 + quad * 8);
      o_acc[nt] = __builtin_amdgcn_mfma_f32_16x16x32_bf16(pf0, vf0, o_acc[nt], 0, 0, 0);
      o_acc[nt] = __builtin_amdgcn_mfma_f32_16x16x32_bf16(pf1, vf1, o_acc[nt], 0, 0, 0);
    }
  }
  // epilogue: normalize, store into [B, S, H*D] layout for the out-proj GEMM
  int b = bh >> 4, h = bh & 15;
#pragma unroll
  for (int r = 0; r < 4; ++r) {
    float inv = 1.f / l_i[r];
    int s = q0 + wave * 16 + quad * 4 + r;
#pragma unroll
    for (int nt = 0; nt < 4; ++nt) {
      int d = nt * 16 + l15;
      O[((size_t)(b * SEQ + s)) * DM + h * HDIM + d] = (bf16)(o_acc[nt][r] * inv);
    }
  }
}

extern "C" void kernel_launch(void* const* d_in, const int* in_sizes, int n_in,
                              void* d_out, int out_size, void* d_ws,
                              size_t ws_size, hipStream_t stream) {
  const float* hidden = (const float*)d_in[0];   // [2,2048,1024] f32
  const float* w_qkv  = (const float*)d_in[1];   // [1024,3072]  f32
  const float* w_out  = (const float*)d_in[2];   // [1024,1024]  f32
  const int*   pos    = (const int*)d_in[3];     // [2,2048,3]   i32
  float* out = (float*)d_out;                    // f32 output

  char* ws = (char*)d_ws;
  bf16* wqkvT  = (bf16*)ws;  ws += (size_t)3072 * 1024 * 2;
  bf16* woutT  = (bf16*)ws;  ws += (size_t)1024 * 1024 * 2;
  bf16* hid_bf = (bf16*)ws;  ws += (size_t)4096 * 1024 * 2;
  bf16* q_ws   = (bf16*)ws;  ws += (size_t)32 * SEQ * HDIM * 2;
  bf16* k_ws   = (bf16*)ws;  ws += (size_t)32 * SEQ * HDIM * 2;
  bf16* vT_ws  = (bf16*)ws;  ws += (size_t)32 * SEQ * HDIM * 2;
  bf16* attn_ws = (bf16*)ws;  // [4096, 1024]

  cvt_f32_bf16<<<dim3(2048), 256, 0, stream>>>(hidden, hid_bf);
  transpose_f32_bf16<<<dim3(48, 16), 256, 0, stream>>>(w_qkv, wqkvT, 1024, 3072);
  transpose_f32_bf16<<<dim3(16, 16), 256, 0, stream>>>(w_out, woutT, 1024, 1024);
  gemm_bt<1><<<dim3(24, 32), 256, 0, stream>>>(
      hid_bf, wqkvT, nullptr, 4096, 3072, 1024, q_ws, k_ws, vT_ws, pos);
  attn_fwd<<<dim3(1024), 256, 0, stream>>>(q_ws, k_ws, vT_ws, attn_ws);
  gemm_bt<0><<<dim3(8, 32), 256, 0, stream>>>(
      attn_ws, woutT, out, 4096, 1024, 1024, nullptr, nullptr, nullptr, nullptr);
}